// Round 1
// baseline (368.046 us; speedup 1.0000x reference)
//
#include <hip/hip_runtime.h>
#include <hip/hip_bf16.h>
#include <cstdint>

typedef __attribute__((ext_vector_type(8))) short bf16x8;
typedef __attribute__((ext_vector_type(4))) float f32x4;

#define MFMA16(a, b, c) __builtin_amdgcn_mfma_f32_16x16x32_bf16(a, b, c, 0, 0, 0)

static __device__ __forceinline__ ushort f2b(float f) {
  union { float f; uint32_t u; } v; v.f = f;
  uint32_t u = v.u;
  uint32_t r = (u + 0x7FFFu + ((u >> 16) & 1u)) >> 16;
  return (ushort)r;
}

// ---------- fp32 -> bf16 convert (n4 = n/4 float4 chunks) ----------
__global__ void cvt_f32_bf16(const float* __restrict__ in, ushort* __restrict__ out, int n4) {
  int i = blockIdx.x * blockDim.x + threadIdx.x;
  if (i >= n4) return;
  const float4 v = ((const float4*)in)[i];
  ushort4 o;
  o.x = f2b(v.x); o.y = f2b(v.y); o.z = f2b(v.z); o.w = f2b(v.w);
  ((ushort4*)out)[i] = o;
}

// ---------- GEMM: C[m][n] = sum_k A[m][k] * W[n][k] + bias[n] ----------
// EPI=0: scatter to q/k/v bf16 [B*H][T][64]   EPI=1: fp32 out [M][N]
template<int EPI>
__global__ __launch_bounds__(256) void gemm_bt(
    const ushort* __restrict__ A,    // [M][K] bf16
    const ushort* __restrict__ W,    // [N][K] bf16
    const float* __restrict__ bias,  // [N]
    int M, int N, int K,
    ushort* __restrict__ q_ws, ushort* __restrict__ k_ws, ushort* __restrict__ v_ws,
    float* __restrict__ out) {
  __shared__ ushort As[128][72];  // pad: 144B row stride -> 2-way bank alias (free)
  __shared__ ushort Bs[128][72];
  const int tid = threadIdx.x;
  const int m0 = blockIdx.y * 128, n0 = blockIdx.x * 128;
  const int lane = tid & 63, w = tid >> 6;
  const int lr = lane & 15, lg = lane >> 4;
  const int wm = (w >> 1) * 64, wn = (w & 1) * 64;
  f32x4 acc[4][4] = {};

  for (int k0 = 0; k0 < K; k0 += 64) {
    __syncthreads();
#pragma unroll
    for (int it = 0; it < 4; ++it) {
      int chunk = tid + it * 256;      // 0..1023
      int r = chunk >> 3;              // 0..127
      int c = (chunk & 7) * 8;         // 0..56
      *(uint4*)&As[r][c] = *(const uint4*)&A[(size_t)(m0 + r) * K + k0 + c];
      *(uint4*)&Bs[r][c] = *(const uint4*)&W[(size_t)(n0 + r) * K + k0 + c];
    }
    __syncthreads();
#pragma unroll
    for (int kk = 0; kk < 2; ++kk) {
      bf16x8 a[4], b[4];
#pragma unroll
      for (int mi = 0; mi < 4; ++mi)
        a[mi] = *(const bf16x8*)&As[wm + mi * 16 + lr][kk * 32 + lg * 8];
#pragma unroll
      for (int ni = 0; ni < 4; ++ni)
        b[ni] = *(const bf16x8*)&Bs[wn + ni * 16 + lr][kk * 32 + lg * 8];
#pragma unroll
      for (int mi = 0; mi < 4; ++mi)
#pragma unroll
        for (int ni = 0; ni < 4; ++ni)
          acc[mi][ni] = MFMA16(a[mi], b[ni], acc[mi][ni]);
    }
  }

#pragma unroll
  for (int mi = 0; mi < 4; ++mi) {
#pragma unroll
    for (int ni = 0; ni < 4; ++ni) {
#pragma unroll
      for (int i = 0; i < 4; ++i) {
        int row = m0 + wm + mi * 16 + lg * 4 + i;  // C/D: row=(lane>>4)*4+reg, col=lane&15
        int col = n0 + wn + ni * 16 + lr;
        float v = acc[mi][ni][i] + bias[col];
        if (EPI == 0) {
          int sel = col >> 10;
          int rem = col & 1023;
          int h = rem >> 6, d = rem & 63;
          int bb = row >> 11, t = row & 2047;
          ushort* dst = (sel == 0) ? q_ws : (sel == 1) ? k_ws : v_ws;
          dst[((size_t)(bb * 16 + h) * 2048 + t) * 64 + d] = f2b(v);
        } else {
          out[(size_t)row * N + col] = v;
        }
      }
    }
  }
}

// ---------- causal flash attention: 1 wave = 16 q rows ----------
__global__ __launch_bounds__(64) void attn_kernel(
    const ushort* __restrict__ Q, const ushort* __restrict__ Km,
    const ushort* __restrict__ V, ushort* __restrict__ O /* [B][T][C] bf16 */) {
  const int bh = blockIdx.x >> 7;   // 0..63
  const int qt = blockIdx.x & 127;  // 0..127
  const int lane = threadIdx.x;
  const int lr = lane & 15, lg = lane >> 4;
  const int q0 = qt * 16;
  const int b = bh >> 4, h = bh & 15;
  const size_t base = (size_t)bh * 2048 * 64;
  const ushort* Qb = Q + base;
  const ushort* Kb = Km + base;
  const ushort* Vb = V + base;

  __shared__ ushort Plds[16][32];

  bf16x8 aq[2];
#pragma unroll
  for (int kk = 0; kk < 2; ++kk)
    aq[kk] = *(const bf16x8*)&Qb[(size_t)(q0 + lr) * 64 + kk * 32 + lg * 8];

  f32x4 o[4] = {};
  float m_i[4], l_i[4];
#pragma unroll
  for (int i = 0; i < 4; ++i) { m_i[i] = -INFINITY; l_i[i] = 0.f; }

  const int kend = q0 + 15;
  for (int k0 = 0; k0 <= kend; k0 += 32) {
    f32x4 s[2];
#pragma unroll
    for (int h2 = 0; h2 < 2; ++h2) {
      bf16x8 bk0 = *(const bf16x8*)&Kb[(size_t)(k0 + h2 * 16 + lr) * 64 + lg * 8];
      bf16x8 bk1 = *(const bf16x8*)&Kb[(size_t)(k0 + h2 * 16 + lr) * 64 + 32 + lg * 8];
      f32x4 t = {};
      t = MFMA16(aq[0], bk0, t);
      t = MFMA16(aq[1], bk1, t);
      int col = k0 + h2 * 16 + lr;
#pragma unroll
      for (int i = 0; i < 4; ++i) {
        int row = q0 + lg * 4 + i;
        t[i] = (col <= row) ? t[i] * 0.125f : -1e30f;
      }
      s[h2] = t;
    }
    float p0[4], p1[4];
#pragma unroll
    for (int i = 0; i < 4; ++i) {
      float mx = fmaxf(s[0][i], s[1][i]);
      mx = fmaxf(mx, __shfl_xor(mx, 1));
      mx = fmaxf(mx, __shfl_xor(mx, 2));
      mx = fmaxf(mx, __shfl_xor(mx, 4));
      mx = fmaxf(mx, __shfl_xor(mx, 8));
      float mnew = fmaxf(m_i[i], mx);
      float a0 = __expf(s[0][i] - mnew);
      float a1 = __expf(s[1][i] - mnew);
      float rs = a0 + a1;
      rs += __shfl_xor(rs, 1);
      rs += __shfl_xor(rs, 2);
      rs += __shfl_xor(rs, 4);
      rs += __shfl_xor(rs, 8);
      float alpha = __expf(m_i[i] - mnew);
      l_i[i] = l_i[i] * alpha + rs;
      m_i[i] = mnew;
      p0[i] = a0;
      p1[i] = a1;
#pragma unroll
      for (int dt = 0; dt < 4; ++dt) o[dt][i] *= alpha;
    }
    // transpose P (D-layout -> A-fragment layout) through LDS
#pragma unroll
    for (int i = 0; i < 4; ++i) {
      Plds[lg * 4 + i][lr] = f2b(p0[i]);
      Plds[lg * 4 + i][lr + 16] = f2b(p1[i]);
    }
    __syncthreads();
    bf16x8 ap = *(const bf16x8*)&Plds[lr][lg * 8];
#pragma unroll
    for (int dt = 0; dt < 4; ++dt) {
      bf16x8 bv;
#pragma unroll
      for (int j = 0; j < 8; ++j)
        bv[j] = (short)Vb[(size_t)(k0 + lg * 8 + j) * 64 + dt * 16 + lr];
      o[dt] = MFMA16(ap, bv, o[dt]);
    }
    __syncthreads();
  }

#pragma unroll
  for (int i = 0; i < 4; ++i) {
    float inv = 1.f / l_i[i];
    int t = q0 + lg * 4 + i;
#pragma unroll
    for (int dt = 0; dt < 4; ++dt)
      O[(size_t)(b * 2048 + t) * 1024 + h * 64 + dt * 16 + lr] = f2b(o[dt][i] * inv);
  }
}

extern "C" void kernel_launch(void* const* d_in, const int* in_sizes, int n_in,
                              void* d_out, int out_size, void* d_ws, size_t ws_size,
                              hipStream_t stream) {
  const float* x = (const float*)d_in[0];
  const float* w_qkv = (const float*)d_in[1];
  const float* b_qkv = (const float*)d_in[2];
  const float* w_proj = (const float*)d_in[3];
  const float* b_proj = (const float*)d_in[4];
  float* out = (float*)d_out;

  char* ws = (char*)d_ws;
  const size_t SZ_X = (size_t)8192 * 1024 * 2;        // 16.78 MB
  const size_t SZ_WQ = (size_t)3072 * 1024 * 2;       // 6.29 MB
  const size_t SZ_WP = (size_t)1024 * 1024 * 2;       // 2.10 MB
  ushort* xb = (ushort*)(ws);                         // x bf16; later reused as attn-out
  ushort* wqb = (ushort*)(ws + SZ_X);
  ushort* wpb = (ushort*)(ws + SZ_X + SZ_WQ);
  ushort* q_ws = (ushort*)(ws + SZ_X + SZ_WQ + SZ_WP);
  ushort* k_ws = q_ws + (size_t)8192 * 1024;
  ushort* v_ws = k_ws + (size_t)8192 * 1024;
  // total ws use: ~75.5 MB

  cvt_f32_bf16<<<8388608 / 4 / 256, 256, 0, stream>>>(x, xb, 8388608 / 4);
  cvt_f32_bf16<<<3145728 / 4 / 256, 256, 0, stream>>>(w_qkv, wqb, 3145728 / 4);
  cvt_f32_bf16<<<1048576 / 4 / 256, 256, 0, stream>>>(w_proj, wpb, 1048576 / 4);

  // QKV: M=8192 N=3072 K=1024, scatter epilogue
  gemm_bt<0><<<dim3(3072 / 128, 8192 / 128), 256, 0, stream>>>(
      xb, wqb, b_qkv, 8192, 3072, 1024, q_ws, k_ws, v_ws, nullptr);

  // attention, output (bf16 [B][T][C]) overwrites xb (GEMM1 already consumed it)
  attn_kernel<<<64 * 128, 64, 0, stream>>>(q_ws, k_ws, v_ws, xb);

  // proj: M=8192 N=1024 K=1024, fp32 + bias to d_out
  gemm_bt<1><<<dim3(1024 / 128, 8192 / 128), 256, 0, stream>>>(
      xb, wpb, b_proj, 8192, 1024, 1024, nullptr, nullptr, nullptr, out);
}